// Round 8
// baseline (240.550 us; speedup 1.0000x reference)
//
#include <hip/hip_runtime.h>

// Problem constants
#define V_N 1000000
#define J_N 23
#define BLK 256
#define NBLK 977            // 976 full blocks (1024 verts each) + tail (576 verts = 144 thr x 4)

// Output layout (flat fp32-element offsets):
// verts_batched (4,V,3) | pose (J,3) | joints_out (J,3) | scale (1) | displacement (3) | local_adjust (V,3)
#define OUT_POSE   12000000
#define OUT_JOINTS 12000069
#define OUT_SCALE  12000138
#define OUT_DISP   12000139
#define OUT_LA     12000142   // byte 48000568: 8B-aligned, NOT 16B-aligned

// Clang vector types for nontemporal builtins (HIP float4/float2 are class
// types and are rejected by __builtin_nontemporal_store).
typedef float v4f __attribute__((ext_vector_type(4)));
typedef float v2f __attribute__((ext_vector_type(2)));

__device__ __constant__ int c_parents[J_N] = {
    -1, 0, 1, 1, 3, 4, 5, 4, 7, 4, 9, 1, 11, 12, 13, 12, 15, 12, 17, 0, 19, 0, 21
};

// ---------------- Stage 1: pose / Rodrigues / FK chain (tiny, 1 block) ----------------
__global__ void stage1_kernel(
    const float* __restrict__ joints_rest,
    const float* __restrict__ j0, const float* __restrict__ j1,
    const float* __restrict__ j2, const float* __restrict__ j3,
    const float* __restrict__ j4, const float* __restrict__ j5,
    const float* __restrict__ j12, const float* __restrict__ j13,
    const float* __restrict__ disp, const float* __restrict__ scale,
    const float* __restrict__ loc,
    float* __restrict__ wsA, float* __restrict__ out)
{
    __shared__ float jr[J_N][3];
    __shared__ float pose[J_N][3];
    __shared__ float R[J_N][9];
    __shared__ float rel[J_N][3];
    __shared__ float G[J_N][12];
    __shared__ float sb[4];
    const int t = threadIdx.x;

    if (t < J_N * 3) {
        ((float*)jr)[t]   = joints_rest[t];
        ((float*)pose)[t] = 0.0f;
    }
    __syncthreads();

    if (t < 27) {   // one thread per (pose row, component)
        const float PI = 3.14159265358979323846f;
        const int   rows[9] = { 0, 1, 2, 3, 11, 4, 5, 12, 13 };
        const float cf[9]   = { PI/2, PI/4, PI/9, PI/3, PI/3, PI/3, PI/3, PI/3, PI/3 };
        int i = t / 3, cmp = t % 3;
        const float* srcs[9];
        srcs[0]=j0; srcs[1]=j1; srcs[2]=j2; srcs[3]=j3; srcs[4]=j3;
        srcs[5]=j4; srcs[6]=j5; srcs[7]=j12; srcs[8]=j13;
        float syz = (rows[i] == 11 && cmp > 0) ? -1.0f : 1.0f;
        pose[rows[i]][cmp] = cf[i] * syz * tanhf(srcs[i][cmp]);
    }
    if (t == 32) {
        sb[0] = 0.0035f * scale[0];
        sb[1] = loc[0] + 0.1f * tanhf(disp[0]);
        sb[2] = loc[1] + 0.1f * tanhf(disp[1]);
        sb[3] = loc[2] + 0.1f * tanhf(disp[2]);
    }
    __syncthreads();

    if (t < J_N) {
        float rx = pose[t][0], ry = pose[t][1], rz = pose[t][2];
        float ang = sqrtf(rx*rx + ry*ry + rz*rz + 1e-12f);
        float inv = 1.0f / ang;
        float x = rx * inv, y = ry * inv, z = rz * inv;
        float s = sinf(ang), c = cosf(ang);
        float K[9]  = { 0.f, -z, y,  z, 0.f, -x,  -y, x, 0.f };
        float K2[9];
        for (int r = 0; r < 3; r++)
            for (int cc = 0; cc < 3; cc++) {
                float a = 0.f;
                for (int k = 0; k < 3; k++) a += K[r*3+k] * K[k*3+cc];
                K2[r*3+cc] = a;
            }
        for (int r = 0; r < 3; r++)
            for (int cc = 0; cc < 3; cc++) {
                float id = (r == cc) ? 1.f : 0.f;
                R[t][r*3+cc] = id + s * K[r*3+cc] + (1.f - c) * K2[r*3+cc];
            }
        int p = c_parents[t];
        for (int cc = 0; cc < 3; cc++)
            rel[t][cc] = (p < 0) ? jr[t][cc] : (jr[t][cc] - jr[p][cc]);
    }
    __syncthreads();

    if (t == 0) {  // serial FK chain (parents precede children)
        for (int r = 0; r < 3; r++) {
            for (int cc = 0; cc < 3; cc++) G[0][r*4+cc] = R[0][r*3+cc];
            G[0][r*4+3] = rel[0][r];
        }
        for (int j = 1; j < J_N; j++) {
            int p = c_parents[j];
            for (int r = 0; r < 3; r++) {
                float g0 = G[p][r*4+0], g1 = G[p][r*4+1], g2 = G[p][r*4+2], g3 = G[p][r*4+3];
                for (int cc = 0; cc < 3; cc++)
                    G[j][r*4+cc] = g0*R[j][0*3+cc] + g1*R[j][1*3+cc] + g2*R[j][2*3+cc];
                G[j][r*4+3] = g0*rel[j][0] + g1*rel[j][1] + g2*rel[j][2] + g3;
            }
        }
    }
    __syncthreads();

    if (t < J_N) {
        for (int r = 0; r < 3; r++) {
            float tc = G[t][r*4+0]*jr[t][0] + G[t][r*4+1]*jr[t][1] + G[t][r*4+2]*jr[t][2];
            wsA[t*12 + r*4 + 0] = G[t][r*4+0];
            wsA[t*12 + r*4 + 1] = G[t][r*4+1];
            wsA[t*12 + r*4 + 2] = G[t][r*4+2];
            wsA[t*12 + r*4 + 3] = G[t][r*4+3] - tc;
            out[OUT_JOINTS + t*3 + r] = sb[0] * G[t][r*4+3] + sb[1+r];
        }
    }
    if (t < J_N * 3) out[OUT_POSE + t] = ((const float*)pose)[t];
    if (t == 0) {
        wsA[276] = sb[0]; wsA[277] = sb[1]; wsA[278] = sb[2]; wsA[279] = sb[3];
        out[OUT_SCALE]  = scale[0];
        out[OUT_DISP+0] = disp[0]; out[OUT_DISP+1] = disp[1]; out[OUT_DISP+2] = disp[2];
    }
}

// ---------------- Stage 2: per-vertex skinning ----------------
// Round-7 (resubmit; r7a was a compile error on nontemporal builtins with HIP
// vector classes -> fixed with ext_vector_type).
// Force memory-level parallelism + stop write pollution:
//  - VPT=4: 4 consecutive vertices = 92 floats = exactly 23 aligned uint4
//    per thread, loaded into a fully-live register array BEFORE any use ->
//    ~23.5KB/wave in flight (15x r0-r6's ~2KB). Wave count drops 4x.
//    No LDS, no barriers.
//  - ALL outputs stored nontemporal (never re-read on device) -> stop the
//    60MB/iter write stream from evicting skin out of L2/L3.
//  - Per-vertex fmaf chain, tanh, A bits identical -> absmax 0.
// NO launch_bounds (spill hazard on this toolchain).
__global__ void stage2_kernel(
    const float* __restrict__ vt,     // v_template   V*3 f32
    const float* __restrict__ skin,   // skinning     V*J f32
    const float* __restrict__ la,     // local_adjust V*3 f32
    const float* __restrict__ wsA,    // A[23][12] + {s, base.xyz}  (uniform reads)
    const int* __restrict__ bsp,      // batch_size
    float* __restrict__ out)
{
    const int gid = blockIdx.x * BLK + threadIdx.x;  // 4-vertex group id
    const int v4  = gid << 2;                        // first vertex of group
    if (v4 >= V_N) return;                           // tail: whole groups only (576%4==0)

    // ---- 23 x uint4: this thread's 4 verts x 23 weights, all issued up front ----
    const uint4* g = (const uint4*)skin + (size_t)gid * 23;   // 368B/thread, 16B-aligned
    uint4 wq[23];
    #pragma unroll
    for (int m = 0; m < 23; m++) wq[m] = g[m];

    // ---- vt / la: 3 x float4 each (v4*12B is 48B-aligned) ----
    const float4* vp = (const float4*)(vt + (size_t)v4 * 3);
    const float4* lp = (const float4*)(la + (size_t)v4 * 3);
    float4 va = vp[0], vb = vp[1], vc = vp[2];
    float4 lA = lp[0], lB = lp[1], lC = lp[2];

    const float sc = wsA[276];                  // uniform -> s_load
    const float bx = wsA[277], by = wsA[278], bz = wsA[279];
    const int   bsz = bsp[0];

    // unpack to constant-indexed arrays (fully unrolled -> stays in registers)
    float vv[12], ll[12];
    vv[0]=va.x; vv[1]=va.y; vv[2] =va.z; vv[3] =va.w;
    vv[4]=vb.x; vv[5]=vb.y; vv[6] =vb.z; vv[7] =vb.w;
    vv[8]=vc.x; vv[9]=vc.y; vv[10]=vc.z; vv[11]=vc.w;
    ll[0]=lA.x; ll[1]=lA.y; ll[2] =lA.z; ll[3] =lA.w;
    ll[4]=lB.x; ll[5]=lB.y; ll[6] =lB.z; ll[7] =lB.w;
    ll[8]=lC.x; ll[9]=lC.y; ll[10]=lC.z; ll[11]=lC.w;

    const float* wf = (const float*)wq;   // constant indices only (unrolled)

    float o[12];
    #pragma unroll
    for (int v = 0; v < 4; v++) {
        float acc[12];
        #pragma unroll
        for (int k = 0; k < 12; k++) acc[k] = 0.f;
        #pragma unroll
        for (int j = 0; j < J_N; j++) {
            const float wj = wf[v * J_N + j];
            const float* Aj = wsA + j * 12;   // uniform -> s_load, 0 VGPRs
            #pragma unroll
            for (int k = 0; k < 12; k++) acc[k] = fmaf(wj, Aj[k], acc[k]);
        }
        const float vx = vv[v*3+0] + 0.1f * tanhf(ll[v*3+0]);
        const float vy = vv[v*3+1] + 0.1f * tanhf(ll[v*3+1]);
        const float vz = vv[v*3+2] + 0.1f * tanhf(ll[v*3+2]);
        const float px = acc[0]*vx + acc[1]*vy + acc[2]*vz  + acc[3];
        const float py = acc[4]*vx + acc[5]*vy + acc[6]*vz  + acc[7];
        const float pz = acc[8]*vx + acc[9]*vy + acc[10]*vz + acc[11];
        o[v*3+0] = fmaf(sc, px, bx);
        o[v*3+1] = fmaf(sc, py, by);
        o[v*3+2] = fmaf(sc, pz, bz);
    }

    // ---- nontemporal stores: outputs are never re-read on device ----
    v4f s0 = { o[0], o[1], o[2],  o[3] };
    v4f s1 = { o[4], o[5], o[6],  o[7] };
    v4f s2 = { o[8], o[9], o[10], o[11] };
    for (int b = 0; b < bsz; b++) {
        v4f* ob = (v4f*)(out + (size_t)b * 3000000u + (size_t)v4 * 3);
        __builtin_nontemporal_store(s0, ob + 0);
        __builtin_nontemporal_store(s1, ob + 1);
        __builtin_nontemporal_store(s2, ob + 2);
    }
    {   // local_adjust passthrough; region byte base 48000568 is 8B-aligned only
        v2f* oe = (v2f*)((char*)out + 48000568ull + (size_t)v4 * 12u);
        v2f e0 = { ll[0],  ll[1]  };
        v2f e1 = { ll[2],  ll[3]  };
        v2f e2 = { ll[4],  ll[5]  };
        v2f e3 = { ll[6],  ll[7]  };
        v2f e4 = { ll[8],  ll[9]  };
        v2f e5 = { ll[10], ll[11] };
        __builtin_nontemporal_store(e0, oe + 0);
        __builtin_nontemporal_store(e1, oe + 1);
        __builtin_nontemporal_store(e2, oe + 2);
        __builtin_nontemporal_store(e3, oe + 3);
        __builtin_nontemporal_store(e4, oe + 4);
        __builtin_nontemporal_store(e5, oe + 5);
    }
}

extern "C" void kernel_launch(void* const* d_in, const int* in_sizes, int n_in,
                              void* d_out, int out_size, void* d_ws, size_t ws_size,
                              hipStream_t stream) {
    const float* vt   = (const float*)d_in[0];
    const float* skin = (const float*)d_in[1];
    const float* jr   = (const float*)d_in[2];
    const float* j0   = (const float*)d_in[3];
    const float* j1   = (const float*)d_in[4];
    const float* j2   = (const float*)d_in[5];
    const float* j3   = (const float*)d_in[6];
    const float* j4   = (const float*)d_in[7];
    const float* j5   = (const float*)d_in[8];
    const float* j12  = (const float*)d_in[9];
    const float* j13  = (const float*)d_in[10];
    const float* la   = (const float*)d_in[11];
    const float* disp = (const float*)d_in[12];
    const float* sc   = (const float*)d_in[13];
    const float* loc  = (const float*)d_in[14];
    const int* bs     = (const int*)d_in[15];

    float* wsA = (float*)d_ws;
    float* out = (float*)d_out;

    stage1_kernel<<<1, 128, 0, stream>>>(jr, j0, j1, j2, j3, j4, j5, j12, j13,
                                         disp, sc, loc, wsA, out);
    stage2_kernel<<<NBLK, BLK, 0, stream>>>(vt, skin, la, wsA, bs, out);
}

// Round 9
// 213.337 us; speedup vs baseline: 1.1276x; 1.1276x over previous
//
#include <hip/hip_runtime.h>

// Problem constants
#define V_N 1000000
#define J_N 23
#define BLK 256
#define NFULL 3906          // blocks 0..3905 full 256-vertex tiles; block 3906 has 64

// Output layout (flat fp32-element offsets):
// verts_batched (4,V,3) | pose (J,3) | joints_out (J,3) | scale (1) | displacement (3) | local_adjust (V,3)
#define OUT_POSE   12000000
#define OUT_JOINTS 12000069
#define OUT_SCALE  12000138
#define OUT_DISP   12000139
#define OUT_LA     12000142   // byte 48000568: 8B-aligned, NOT 16B-aligned

// Clang vector type for nontemporal load (HIP uint4 is a class type, rejected
// by __builtin_nontemporal_load).
typedef unsigned int v4u __attribute__((ext_vector_type(4)));

__device__ __constant__ int c_parents[J_N] = {
    -1, 0, 1, 1, 3, 4, 5, 4, 7, 4, 9, 1, 11, 12, 13, 12, 15, 12, 17, 0, 19, 0, 21
};

// ---------------- Stage 1: pose / Rodrigues / FK chain (tiny, 1 block) ----------------
__global__ void stage1_kernel(
    const float* __restrict__ joints_rest,
    const float* __restrict__ j0, const float* __restrict__ j1,
    const float* __restrict__ j2, const float* __restrict__ j3,
    const float* __restrict__ j4, const float* __restrict__ j5,
    const float* __restrict__ j12, const float* __restrict__ j13,
    const float* __restrict__ disp, const float* __restrict__ scale,
    const float* __restrict__ loc,
    float* __restrict__ wsA, float* __restrict__ out)
{
    __shared__ float jr[J_N][3];
    __shared__ float pose[J_N][3];
    __shared__ float R[J_N][9];
    __shared__ float rel[J_N][3];
    __shared__ float G[J_N][12];
    __shared__ float sb[4];
    const int t = threadIdx.x;

    if (t < J_N * 3) {
        ((float*)jr)[t]   = joints_rest[t];
        ((float*)pose)[t] = 0.0f;
    }
    __syncthreads();

    if (t < 27) {   // one thread per (pose row, component)
        const float PI = 3.14159265358979323846f;
        const int   rows[9] = { 0, 1, 2, 3, 11, 4, 5, 12, 13 };
        const float cf[9]   = { PI/2, PI/4, PI/9, PI/3, PI/3, PI/3, PI/3, PI/3, PI/3 };
        int i = t / 3, cmp = t % 3;
        const float* srcs[9];
        srcs[0]=j0; srcs[1]=j1; srcs[2]=j2; srcs[3]=j3; srcs[4]=j3;
        srcs[5]=j4; srcs[6]=j5; srcs[7]=j12; srcs[8]=j13;
        float syz = (rows[i] == 11 && cmp > 0) ? -1.0f : 1.0f;
        pose[rows[i]][cmp] = cf[i] * syz * tanhf(srcs[i][cmp]);
    }
    if (t == 32) {
        sb[0] = 0.0035f * scale[0];
        sb[1] = loc[0] + 0.1f * tanhf(disp[0]);
        sb[2] = loc[1] + 0.1f * tanhf(disp[1]);
        sb[3] = loc[2] + 0.1f * tanhf(disp[2]);
    }
    __syncthreads();

    if (t < J_N) {
        float rx = pose[t][0], ry = pose[t][1], rz = pose[t][2];
        float ang = sqrtf(rx*rx + ry*ry + rz*rz + 1e-12f);
        float inv = 1.0f / ang;
        float x = rx * inv, y = ry * inv, z = rz * inv;
        float s = sinf(ang), c = cosf(ang);
        float K[9]  = { 0.f, -z, y,  z, 0.f, -x,  -y, x, 0.f };
        float K2[9];
        for (int r = 0; r < 3; r++)
            for (int cc = 0; cc < 3; cc++) {
                float a = 0.f;
                for (int k = 0; k < 3; k++) a += K[r*3+k] * K[k*3+cc];
                K2[r*3+cc] = a;
            }
        for (int r = 0; r < 3; r++)
            for (int cc = 0; cc < 3; cc++) {
                float id = (r == cc) ? 1.f : 0.f;
                R[t][r*3+cc] = id + s * K[r*3+cc] + (1.f - c) * K2[r*3+cc];
            }
        int p = c_parents[t];
        for (int cc = 0; cc < 3; cc++)
            rel[t][cc] = (p < 0) ? jr[t][cc] : (jr[t][cc] - jr[p][cc]);
    }
    __syncthreads();

    if (t == 0) {  // serial FK chain (parents precede children)
        for (int r = 0; r < 3; r++) {
            for (int cc = 0; cc < 3; cc++) G[0][r*4+cc] = R[0][r*3+cc];
            G[0][r*4+3] = rel[0][r];
        }
        for (int j = 1; j < J_N; j++) {
            int p = c_parents[j];
            for (int r = 0; r < 3; r++) {
                float g0 = G[p][r*4+0], g1 = G[p][r*4+1], g2 = G[p][r*4+2], g3 = G[p][r*4+3];
                for (int cc = 0; cc < 3; cc++)
                    G[j][r*4+cc] = g0*R[j][0*3+cc] + g1*R[j][1*3+cc] + g2*R[j][2*3+cc];
                G[j][r*4+3] = g0*rel[j][0] + g1*rel[j][1] + g2*rel[j][2] + g3;
            }
        }
    }
    __syncthreads();

    if (t < J_N) {
        for (int r = 0; r < 3; r++) {
            float tc = G[t][r*4+0]*jr[t][0] + G[t][r*4+1]*jr[t][1] + G[t][r*4+2]*jr[t][2];
            wsA[t*12 + r*4 + 0] = G[t][r*4+0];
            wsA[t*12 + r*4 + 1] = G[t][r*4+1];
            wsA[t*12 + r*4 + 2] = G[t][r*4+2];
            wsA[t*12 + r*4 + 3] = G[t][r*4+3] - tc;
            out[OUT_JOINTS + t*3 + r] = sb[0] * G[t][r*4+3] + sb[1+r];
        }
    }
    if (t < J_N * 3) out[OUT_POSE + t] = ((const float*)pose)[t];
    if (t == 0) {
        wsA[276] = sb[0]; wsA[277] = sb[1]; wsA[278] = sb[2]; wsA[279] = sb[3];
        out[OUT_SCALE]  = scale[0];
        out[OUT_DISP+0] = disp[0]; out[OUT_DISP+1] = disp[1]; out[OUT_DISP+2] = disp[2];
    }
}

// ---------------- Stage 2: per-vertex skinning ----------------
// Round-9: best-measured structure (round-1 bench, 55.6-57.3us) + ONE change:
// NONTEMPORAL LOADS on the skin staging.
// Rationale: skin (92MB) has zero intra-iteration reuse; its L3 residency is
// what the 60MB/iter write stream thrashes (steady state: writes evict ~57MB
// of input -> FETCH=57MB every iteration). nt loads keep skin OUT of the LLC
// so vt+la+outputs (~84MB) become fully L3-resident: the output drain
// (WRITE_SIZE 58.7MB) should collapse and the HBM pattern becomes a clean
// read stream. Reads cannot amplify (each 64B line is touched by exactly one
// wave instruction in this staging pattern), unlike round-8's NT stores.
// NO launch_bounds (spill hazard on this toolchain).
__global__ void stage2_kernel(
    const float* __restrict__ vt,     // v_template   V*3 f32
    const float* __restrict__ skin,   // skinning     V*J f32
    const float* __restrict__ la,     // local_adjust V*3 f32
    const float* __restrict__ wsA,    // A[23][12] + {s, base.xyz}  (uniform reads)
    const int* __restrict__ bsp,      // batch_size
    float* __restrict__ out)
{
    __shared__ v4u s_sk[1472];        // 23552 B -> 6 blocks/CU

    const int tid = threadIdx.x;
    const int blk = blockIdx.x;
    const int v0  = blk * BLK;
    const int v   = v0 + tid;

    const v4u* g = (const v4u*)skin + (size_t)blk * 1472;

    float cvx = 0.f, cvy = 0.f, cvz = 0.f, clx = 0.f, cly = 0.f, clz = 0.f;

    if (blk < NFULL) {
        // 6 independent 16B nt loads in flight before any LDS write
        v4u r0 = __builtin_nontemporal_load(g + tid);
        v4u r1 = __builtin_nontemporal_load(g + tid + 256);
        v4u r2 = __builtin_nontemporal_load(g + tid + 512);
        v4u r3 = __builtin_nontemporal_load(g + tid + 768);
        v4u r4 = __builtin_nontemporal_load(g + tid + 1024);
        v4u r5 = (v4u){0u, 0u, 0u, 0u};
        if (tid < 192) r5 = __builtin_nontemporal_load(g + tid + 1280);
        // per-thread direct loads (normal, cacheable), consumed after barrier
        const float* vp = vt + (size_t)v * 3;
        const float* lp = la + (size_t)v * 3;
        cvx = vp[0]; cvy = vp[1]; cvz = vp[2];
        clx = lp[0]; cly = lp[1]; clz = lp[2];

        s_sk[tid]        = r0;
        s_sk[tid + 256]  = r1;
        s_sk[tid + 512]  = r2;
        s_sk[tid + 768]  = r3;
        s_sk[tid + 1024] = r4;
        if (tid < 192) s_sk[tid + 1280] = r5;
    } else {                          // tail block: 64 verts
        for (int i = tid; i < 368; i += BLK)
            s_sk[i] = __builtin_nontemporal_load(g + i);
        if (v < V_N) {
            const float* vp = vt + (size_t)v * 3;
            const float* lp = la + (size_t)v * 3;
            cvx = vp[0]; cvy = vp[1]; cvz = vp[2];
            clx = lp[0]; cly = lp[1]; clz = lp[2];
        }
    }
    __syncthreads();

    if (v < V_N) {
        const float* wr = (const float*)s_sk + tid * J_N;  // stride 23: 2-way alias, free
        float acc[12];
        #pragma unroll
        for (int k = 0; k < 12; k++) acc[k] = 0.f;
        #pragma unroll
        for (int j = 0; j < J_N; j++) {
            const float wj = wr[j];
            const float* Aj = wsA + j * 12;   // uniform address -> s_load, 0 VGPRs
            #pragma unroll
            for (int k = 0; k < 12; k++) acc[k] = fmaf(wj, Aj[k], acc[k]);
        }
        const float vx = cvx + 0.1f * tanhf(clx);
        const float vy = cvy + 0.1f * tanhf(cly);
        const float vz = cvz + 0.1f * tanhf(clz);
        const float px = acc[0]*vx + acc[1]*vy + acc[2]*vz  + acc[3];
        const float py = acc[4]*vx + acc[5]*vy + acc[6]*vz  + acc[7];
        const float pz = acc[8]*vx + acc[9]*vy + acc[10]*vz + acc[11];
        const float sc = wsA[276];            // uniform
        const float ox = fmaf(sc, px, wsA[277]);
        const float oy = fmaf(sc, py, wsA[278]);
        const float oz = fmaf(sc, pz, wsA[279]);

        const int bsz = bsp[0];
        float* ob = out + (size_t)v * 3;
        for (int b = 0; b < bsz; b++) {
            ob[0] = ox; ob[1] = oy; ob[2] = oz;   // dwordx3, coalesced, cacheable
            ob += 3000000;                        // V*3 floats per batch copy
        }
        float* oe = out + OUT_LA + (size_t)v * 3; // local_adjust passthrough
        oe[0] = clx; oe[1] = cly; oe[2] = clz;
    }
}

extern "C" void kernel_launch(void* const* d_in, const int* in_sizes, int n_in,
                              void* d_out, int out_size, void* d_ws, size_t ws_size,
                              hipStream_t stream) {
    const float* vt   = (const float*)d_in[0];
    const float* skin = (const float*)d_in[1];
    const float* jr   = (const float*)d_in[2];
    const float* j0   = (const float*)d_in[3];
    const float* j1   = (const float*)d_in[4];
    const float* j2   = (const float*)d_in[5];
    const float* j3   = (const float*)d_in[6];
    const float* j4   = (const float*)d_in[7];
    const float* j5   = (const float*)d_in[8];
    const float* j12  = (const float*)d_in[9];
    const float* j13  = (const float*)d_in[10];
    const float* la   = (const float*)d_in[11];
    const float* disp = (const float*)d_in[12];
    const float* sc   = (const float*)d_in[13];
    const float* loc  = (const float*)d_in[14];
    const int* bs     = (const int*)d_in[15];

    float* wsA = (float*)d_ws;
    float* out = (float*)d_out;

    stage1_kernel<<<1, 128, 0, stream>>>(jr, j0, j1, j2, j3, j4, j5, j12, j13,
                                         disp, sc, loc, wsA, out);
    stage2_kernel<<<(V_N + BLK - 1) / BLK, BLK, 0, stream>>>(vt, skin, la, wsA, bs, out);
}

// Round 10
// 209.982 us; speedup vs baseline: 1.1456x; 1.0160x over previous
//
#include <hip/hip_runtime.h>

// Problem constants
#define V_N 1000000
#define J_N 23
#define BLK 256
#define NFULL 3906          // blocks 0..3905 full 256-vertex tiles; block 3906 has 64

// Output layout (flat fp32-element offsets):
// verts_batched (4,V,3) | pose (J,3) | joints_out (J,3) | scale (1) | displacement (3) | local_adjust (V,3)
#define OUT_POSE   12000000
#define OUT_JOINTS 12000069
#define OUT_SCALE  12000138
#define OUT_DISP   12000139
#define OUT_LA     12000142   // byte 48000568: 8B-aligned, NOT 16B-aligned

__device__ __constant__ int c_parents[J_N] = {
    -1, 0, 1, 1, 3, 4, 5, 4, 7, 4, 9, 1, 11, 12, 13, 12, 15, 12, 17, 0, 19, 0, 21
};

// Direct HBM->LDS DMA, 16B per lane, NT cache policy (aux=2: CPol NT bit on
// gfx94x+; cache hints cannot affect correctness). Dest must be wave-uniform
// base + lane*16 -- all call sites below satisfy this (linear staging).
__device__ __forceinline__ void gload_lds16_nt(const void* g, void* l) {
    __builtin_amdgcn_global_load_lds(
        (const __attribute__((address_space(1))) unsigned int*)g,
        (__attribute__((address_space(3))) unsigned int*)l,
        16, 0, 2);
}

// ---------------- Stage 1: pose / Rodrigues / FK chain (tiny, 1 block) ----------------
__global__ void stage1_kernel(
    const float* __restrict__ joints_rest,
    const float* __restrict__ j0, const float* __restrict__ j1,
    const float* __restrict__ j2, const float* __restrict__ j3,
    const float* __restrict__ j4, const float* __restrict__ j5,
    const float* __restrict__ j12, const float* __restrict__ j13,
    const float* __restrict__ disp, const float* __restrict__ scale,
    const float* __restrict__ loc,
    float* __restrict__ wsA, float* __restrict__ out)
{
    __shared__ float jr[J_N][3];
    __shared__ float pose[J_N][3];
    __shared__ float R[J_N][9];
    __shared__ float rel[J_N][3];
    __shared__ float G[J_N][12];
    __shared__ float sb[4];
    const int t = threadIdx.x;

    if (t < J_N * 3) {
        ((float*)jr)[t]   = joints_rest[t];
        ((float*)pose)[t] = 0.0f;
    }
    __syncthreads();

    if (t < 27) {   // one thread per (pose row, component)
        const float PI = 3.14159265358979323846f;
        const int   rows[9] = { 0, 1, 2, 3, 11, 4, 5, 12, 13 };
        const float cf[9]   = { PI/2, PI/4, PI/9, PI/3, PI/3, PI/3, PI/3, PI/3, PI/3 };
        int i = t / 3, cmp = t % 3;
        const float* srcs[9];
        srcs[0]=j0; srcs[1]=j1; srcs[2]=j2; srcs[3]=j3; srcs[4]=j3;
        srcs[5]=j4; srcs[6]=j5; srcs[7]=j12; srcs[8]=j13;
        float syz = (rows[i] == 11 && cmp > 0) ? -1.0f : 1.0f;
        pose[rows[i]][cmp] = cf[i] * syz * tanhf(srcs[i][cmp]);
    }
    if (t == 32) {
        sb[0] = 0.0035f * scale[0];
        sb[1] = loc[0] + 0.1f * tanhf(disp[0]);
        sb[2] = loc[1] + 0.1f * tanhf(disp[1]);
        sb[3] = loc[2] + 0.1f * tanhf(disp[2]);
    }
    __syncthreads();

    if (t < J_N) {
        float rx = pose[t][0], ry = pose[t][1], rz = pose[t][2];
        float ang = sqrtf(rx*rx + ry*ry + rz*rz + 1e-12f);
        float inv = 1.0f / ang;
        float x = rx * inv, y = ry * inv, z = rz * inv;
        float s = sinf(ang), c = cosf(ang);
        float K[9]  = { 0.f, -z, y,  z, 0.f, -x,  -y, x, 0.f };
        float K2[9];
        for (int r = 0; r < 3; r++)
            for (int cc = 0; cc < 3; cc++) {
                float a = 0.f;
                for (int k = 0; k < 3; k++) a += K[r*3+k] * K[k*3+cc];
                K2[r*3+cc] = a;
            }
        for (int r = 0; r < 3; r++)
            for (int cc = 0; cc < 3; cc++) {
                float id = (r == cc) ? 1.f : 0.f;
                R[t][r*3+cc] = id + s * K[r*3+cc] + (1.f - c) * K2[r*3+cc];
            }
        int p = c_parents[t];
        for (int cc = 0; cc < 3; cc++)
            rel[t][cc] = (p < 0) ? jr[t][cc] : (jr[t][cc] - jr[p][cc]);
    }
    __syncthreads();

    if (t == 0) {  // serial FK chain (parents precede children)
        for (int r = 0; r < 3; r++) {
            for (int cc = 0; cc < 3; cc++) G[0][r*4+cc] = R[0][r*3+cc];
            G[0][r*4+3] = rel[0][r];
        }
        for (int j = 1; j < J_N; j++) {
            int p = c_parents[j];
            for (int r = 0; r < 3; r++) {
                float g0 = G[p][r*4+0], g1 = G[p][r*4+1], g2 = G[p][r*4+2], g3 = G[p][r*4+3];
                for (int cc = 0; cc < 3; cc++)
                    G[j][r*4+cc] = g0*R[j][0*3+cc] + g1*R[j][1*3+cc] + g2*R[j][2*3+cc];
                G[j][r*4+3] = g0*rel[j][0] + g1*rel[j][1] + g2*rel[j][2] + g3;
            }
        }
    }
    __syncthreads();

    if (t < J_N) {
        for (int r = 0; r < 3; r++) {
            float tc = G[t][r*4+0]*jr[t][0] + G[t][r*4+1]*jr[t][1] + G[t][r*4+2]*jr[t][2];
            wsA[t*12 + r*4 + 0] = G[t][r*4+0];
            wsA[t*12 + r*4 + 1] = G[t][r*4+1];
            wsA[t*12 + r*4 + 2] = G[t][r*4+2];
            wsA[t*12 + r*4 + 3] = G[t][r*4+3] - tc;
            out[OUT_JOINTS + t*3 + r] = sb[0] * G[t][r*4+3] + sb[1+r];
        }
    }
    if (t < J_N * 3) out[OUT_POSE + t] = ((const float*)pose)[t];
    if (t == 0) {
        wsA[276] = sb[0]; wsA[277] = sb[1]; wsA[278] = sb[2]; wsA[279] = sb[3];
        out[OUT_SCALE]  = scale[0];
        out[OUT_DISP+0] = disp[0]; out[OUT_DISP+1] = disp[1]; out[OUT_DISP+2] = disp[2];
    }
}

// ---------------- Stage 2: per-vertex skinning ----------------
// Round-10: round-9 winner (NT skin path; 213.3us total, stage2 ~50us) with
// ONE change: skin staging via global_load_lds (direct HBM->LDS DMA, m97
// path) instead of the VGPR round-trip. No VGPR staging regs, no ds_writes,
// loads stay vmcnt-counted until the barrier drain. aux=2 keeps the NT
// policy that produced round 9's win (skin bypasses LLC -> vt/la/outputs
// stay L3-resident; write drain collapses).
// NO launch_bounds (spill hazard on this toolchain).
__global__ void stage2_kernel(
    const float* __restrict__ vt,     // v_template   V*3 f32
    const float* __restrict__ skin,   // skinning     V*J f32
    const float* __restrict__ la,     // local_adjust V*3 f32
    const float* __restrict__ wsA,    // A[23][12] + {s, base.xyz}  (uniform reads)
    const int* __restrict__ bsp,      // batch_size
    float* __restrict__ out)
{
    __shared__ uint4 s_sk[1472];      // 23552 B -> 6 blocks/CU

    const int tid = threadIdx.x;
    const int blk = blockIdx.x;
    const int v0  = blk * BLK;
    const int v   = v0 + tid;

    const uint4* g = (const uint4*)skin + (size_t)blk * 1472;

    // ---- skin staging: direct-to-LDS DMA (wave-uniform base + lane*16) ----
    if (blk < NFULL) {
        gload_lds16_nt(g + tid,        s_sk + tid);
        gload_lds16_nt(g + tid + 256,  s_sk + tid + 256);
        gload_lds16_nt(g + tid + 512,  s_sk + tid + 512);
        gload_lds16_nt(g + tid + 768,  s_sk + tid + 768);
        gload_lds16_nt(g + tid + 1024, s_sk + tid + 1024);
        if (tid < 192)
            gload_lds16_nt(g + tid + 1280, s_sk + tid + 1280);
    } else {                          // tail block: 64 verts (368 chunks)
        for (int i = tid; i < 368; i += BLK)
            gload_lds16_nt(g + i, s_sk + i);
    }

    // ---- vertex + local_adjust direct to registers (cacheable; overlap DMA) ----
    float cvx = 0.f, cvy = 0.f, cvz = 0.f, clx = 0.f, cly = 0.f, clz = 0.f;
    if (v < V_N) {
        const float* vp = vt + (size_t)v * 3;
        const float* lp = la + (size_t)v * 3;
        cvx = vp[0]; cvy = vp[1]; cvz = vp[2];
        clx = lp[0]; cly = lp[1]; clz = lp[2];
    }
    __syncthreads();   // drains vmcnt (DMA complete) + barrier

    if (v < V_N) {
        const float* wr = (const float*)s_sk + tid * J_N;  // stride 23: 2-way alias, free
        float acc[12];
        #pragma unroll
        for (int k = 0; k < 12; k++) acc[k] = 0.f;
        #pragma unroll
        for (int j = 0; j < J_N; j++) {
            const float wj = wr[j];
            const float* Aj = wsA + j * 12;   // uniform address -> s_load, 0 VGPRs
            #pragma unroll
            for (int k = 0; k < 12; k++) acc[k] = fmaf(wj, Aj[k], acc[k]);
        }
        const float vx = cvx + 0.1f * tanhf(clx);
        const float vy = cvy + 0.1f * tanhf(cly);
        const float vz = cvz + 0.1f * tanhf(clz);
        const float px = acc[0]*vx + acc[1]*vy + acc[2]*vz  + acc[3];
        const float py = acc[4]*vx + acc[5]*vy + acc[6]*vz  + acc[7];
        const float pz = acc[8]*vx + acc[9]*vy + acc[10]*vz + acc[11];
        const float sc = wsA[276];            // uniform
        const float ox = fmaf(sc, px, wsA[277]);
        const float oy = fmaf(sc, py, wsA[278]);
        const float oz = fmaf(sc, pz, wsA[279]);

        const int bsz = bsp[0];
        float* ob = out + (size_t)v * 3;
        for (int b = 0; b < bsz; b++) {
            ob[0] = ox; ob[1] = oy; ob[2] = oz;   // dwordx3, coalesced, cacheable
            ob += 3000000;                        // V*3 floats per batch copy
        }
        float* oe = out + OUT_LA + (size_t)v * 3; // local_adjust passthrough
        oe[0] = clx; oe[1] = cly; oe[2] = clz;
    }
}

extern "C" void kernel_launch(void* const* d_in, const int* in_sizes, int n_in,
                              void* d_out, int out_size, void* d_ws, size_t ws_size,
                              hipStream_t stream) {
    const float* vt   = (const float*)d_in[0];
    const float* skin = (const float*)d_in[1];
    const float* jr   = (const float*)d_in[2];
    const float* j0   = (const float*)d_in[3];
    const float* j1   = (const float*)d_in[4];
    const float* j2   = (const float*)d_in[5];
    const float* j3   = (const float*)d_in[6];
    const float* j4   = (const float*)d_in[7];
    const float* j5   = (const float*)d_in[8];
    const float* j12  = (const float*)d_in[9];
    const float* j13  = (const float*)d_in[10];
    const float* la   = (const float*)d_in[11];
    const float* disp = (const float*)d_in[12];
    const float* sc   = (const float*)d_in[13];
    const float* loc  = (const float*)d_in[14];
    const int* bs     = (const int*)d_in[15];

    float* wsA = (float*)d_ws;
    float* out = (float*)d_out;

    stage1_kernel<<<1, 128, 0, stream>>>(jr, j0, j1, j2, j3, j4, j5, j12, j13,
                                         disp, sc, loc, wsA, out);
    stage2_kernel<<<(V_N + BLK - 1) / BLK, BLK, 0, stream>>>(vt, skin, la, wsA, bs, out);
}